// Round 5
// baseline (329.916 us; speedup 1.0000x reference)
//
#include <hip/hip_runtime.h>
#include <cstddef>

static constexpr int N_NODES = 50000;
static constexpr int E_EDGES = 640000;
static constexpr int F = 128;

typedef __bf16 b8 __attribute__((ext_vector_type(8)));
typedef float  f4 __attribute__((ext_vector_type(4)));

__device__ inline unsigned short f2bf(float f) {           // RTN-even
    unsigned u = __float_as_uint(f);
    u += 0x7FFF + ((u >> 16) & 1);
    return (unsigned short)(u >> 16);
}
__device__ inline float bflo(unsigned u) { return __uint_as_float(u << 16); }
__device__ inline float bfhi(unsigned u) { return __uint_as_float(u & 0xFFFF0000u); }

__device__ inline void acc8(float* s, uint4 u) {
    s[0] += bflo(u.x); s[1] += bfhi(u.x);
    s[2] += bflo(u.y); s[3] += bfhi(u.y);
    s[4] += bflo(u.z); s[5] += bfhi(u.z);
    s[6] += bflo(u.w); s[7] += bfhi(u.w);
}

// ---------------- prep mega-kernel: count_deg | x->bf16 | pack W1 | pack W2 ----------------
// Blocks [0,2500): degree histogram. [2500,5625): f32->bf16 convert of x.
// [5625,5641): pack W1 into MFMA B-frag order. [5641,5649): pack W2.
template<int BN>
__device__ inline void pack_w_body(int t, const float* __restrict__ Wl,
                                   const float* __restrict__ Wr, uint4* __restrict__ Bp) {
    constexpr int NTg = BN / 16;
    int wid = t >> 6, lane = t & 63;
    if (wid >= 8 * NTg) return;
    int kq = lane >> 4, m = lane & 15;
    int kt = wid / NTg, nt = wid % NTg;
    unsigned short tmp[8];
#pragma unroll
    for (int j = 0; j < 8; ++j) {
        int k = kt * 32 + kq * 8 + j;
        const float* W = (k < 128) ? Wl : Wr;
        tmp[j] = f2bf(W[(size_t)(k & 127) * BN + nt * 16 + m]);
    }
    uint4 u;
    u.x = tmp[0] | ((unsigned)tmp[1] << 16);
    u.y = tmp[2] | ((unsigned)tmp[3] << 16);
    u.z = tmp[4] | ((unsigned)tmp[5] << 16);
    u.w = tmp[6] | ((unsigned)tmp[7] << 16);
    Bp[wid * 64 + lane] = u;
}

__global__ __launch_bounds__(256)
void prep(const int* __restrict__ ei, int* __restrict__ deg,
          const float* __restrict__ x, uint4* __restrict__ xb,
          const float* __restrict__ W1l, const float* __restrict__ W1r, uint4* __restrict__ Bp1,
          const float* __restrict__ W2l, const float* __restrict__ W2r, uint4* __restrict__ Bp2) {
    int b = blockIdx.x, tid = threadIdx.x;
    if (b < 2500) {                       // count_deg (E = 2500*256 exact)
        int e = b * 256 + tid;
        atomicAdd(&deg[ei[E_EDGES + e]], 1);
    } else if (b < 5625) {                // f32 -> bf16 (n8 = 3125*256 exact)
        int i = (b - 2500) * 256 + tid;
        const float4* s = (const float4*)x + (size_t)i * 2;
        float4 v0 = s[0], v1 = s[1];
        uint4 u;
        u.x = f2bf(v0.x) | ((unsigned)f2bf(v0.y) << 16);
        u.y = f2bf(v0.z) | ((unsigned)f2bf(v0.w) << 16);
        u.z = f2bf(v1.x) | ((unsigned)f2bf(v1.y) << 16);
        u.w = f2bf(v1.z) | ((unsigned)f2bf(v1.w) << 16);
        xb[i] = u;
    } else if (b < 5641) {                // pack W1 (64 waves)
        pack_w_body<128>((b - 5625) * 256 + tid, W1l, W1r, Bp1);
    } else {                              // pack W2 (32 waves)
        pack_w_body<64>((b - 5641) * 256 + tid, W2l, W2r, Bp2);
    }
}

// ---------------- single-block exclusive scan: deg -> rowptr ----------------
__global__ __launch_bounds__(1024)
void scan_block(const int* __restrict__ deg, int* __restrict__ rowptr, int N, int E) {
    __shared__ int part[1024];
    const int CH = (N + 1023) / 1024;     // 49
    int tid  = threadIdx.x;
    int base = tid * CH;
    int sum = 0;
    for (int i = 0; i < CH; ++i) {
        int idx = base + i;
        if (idx < N) sum += deg[idx];
    }
    part[tid] = sum;
    __syncthreads();
    for (int off = 1; off < 1024; off <<= 1) {
        int t = (tid >= off) ? part[tid - off] : 0;
        __syncthreads();
        part[tid] += t;
        __syncthreads();
    }
    int run = part[tid] - sum;            // exclusive offset for this chunk
    for (int i = 0; i < CH; ++i) {
        int idx = base + i;
        if (idx < N) { rowptr[idx] = run; run += deg[idx]; }
    }
    if (tid == 0) rowptr[N] = E;
}

__global__ void fill_csr(const int* __restrict__ ei, const int* __restrict__ rowptr,
                         int* __restrict__ cursor, int* __restrict__ col, int E) {
    int e = blockIdx.x * blockDim.x + threadIdx.x;
    if (e >= E) return;
    int s = ei[e], d = ei[E + e];
    int off = atomicAdd(&cursor[d], 1);
    col[rowptr[d] + off] = s;
}

// ---------------- Mean aggregation: one wave per node, dwordx4 gather ----------------
// Row = 128 bf16 = 16 uint4. 16 lanes cover a row; 4 neighbor slots (g) per
// wave, unrolled x2 -> 8 rows in flight. Reduce via shfl_xor 16/32.
__global__ __launch_bounds__(256)
void csr_mean_bf(const uint4* __restrict__ feat,
                 const int* __restrict__ rowptr,
                 const int* __restrict__ col,
                 uint4* __restrict__ agg, int N) {
    int wid = (int)((blockIdx.x * 256u + threadIdx.x) >> 6);
    if (wid >= N) return;
    int lane = threadIdx.x & 63;
    int c = lane & 15;     // uint4 chunk within row
    int g = lane >> 4;     // neighbor slot 0..3

    int jb = rowptr[wid], je = rowptr[wid + 1];
    float s0[8] = {0.f, 0.f, 0.f, 0.f, 0.f, 0.f, 0.f, 0.f};
    float s1[8] = {0.f, 0.f, 0.f, 0.f, 0.f, 0.f, 0.f, 0.f};
    for (int j = jb; j < je; j += 8) {
        int i0 = j + g, i1 = j + 4 + g;
        if (i0 < je) {
            uint4 u = feat[(size_t)col[i0] * 16 + c];
            acc8(s0, u);
        }
        if (i1 < je) {
            uint4 u = feat[(size_t)col[i1] * 16 + c];
            acc8(s1, u);
        }
    }
#pragma unroll
    for (int k = 0; k < 8; ++k) s0[k] += s1[k];
#pragma unroll
    for (int k = 0; k < 8; ++k) {
        s0[k] += __shfl_xor(s0[k], 16);
        s0[k] += __shfl_xor(s0[k], 32);
    }
    int d = je - jb;
    float inv = 1.0f / (float)(d > 0 ? d : 1);
    if (g == 0) {
        uint4 o;
        o.x = f2bf(s0[0] * inv) | ((unsigned)f2bf(s0[1] * inv) << 16);
        o.y = f2bf(s0[2] * inv) | ((unsigned)f2bf(s0[3] * inv) << 16);
        o.z = f2bf(s0[4] * inv) | ((unsigned)f2bf(s0[5] * inv) << 16);
        o.w = f2bf(s0[6] * inv) | ((unsigned)f2bf(s0[7] * inv) << 16);
        agg[(size_t)wid * 16 + c] = o;
    }
}

// ---------------- MFMA GEMM: out = [agg|self]@[Wl;Wr] + bias ----------------
// One wave per (16-row tile, 64-col half). No LDS, no barriers.
template<int BN, bool RELU, bool OUTBF>
__global__ __launch_bounds__(256)
void sage_mfma(const unsigned short* __restrict__ aggb,
               const unsigned short* __restrict__ selfb,
               const unsigned short* __restrict__ Bp,
               const float* __restrict__ bias,
               void* __restrict__ outp, int N) {
    constexpr int NT  = 4;        // col-tiles per wave (64 cols)
    constexpr int NH  = BN / 64;  // col-halves
    constexpr int NTg = BN / 16;
    int gw = (int)((blockIdx.x * 256u + threadIdx.x) >> 6);
    int wt = gw / NH, ch = gw - wt * NH;
    int row0 = wt * 16;
    if (row0 >= N) return;
    int lane = threadIdx.x & 63;
    int m = lane & 15, kq = lane >> 4;

    const unsigned short* arow_a = aggb  + (size_t)(row0 + m) * F + kq * 8;
    const unsigned short* arow_s = selfb + (size_t)(row0 + m) * F + kq * 8;

    f4 zero = {0.f, 0.f, 0.f, 0.f};
    f4 acc[NT] = {zero, zero, zero, zero};

#pragma unroll
    for (int kt = 0; kt < 8; ++kt) {
        const unsigned short* ap = (kt < 4) ? (arow_a + kt * 32) : (arow_s + (kt - 4) * 32);
        b8 a = *((const b8*)ap);
#pragma unroll
        for (int nt = 0; nt < NT; ++nt) {
            b8 b = *((const b8*)(Bp + ((size_t)(kt * NTg + ch * NT + nt) * 64 + lane) * 8));
            acc[nt] = __builtin_amdgcn_mfma_f32_16x16x32_bf16(a, b, acc[nt], 0, 0, 0);
        }
    }

    int rowb = row0 + kq * 4;
#pragma unroll
    for (int nt = 0; nt < NT; ++nt) {
        int c = ch * 64 + nt * 16 + m;
        float bv = bias[c];
#pragma unroll
        for (int r = 0; r < 4; ++r) {
            float v = acc[nt][r] + bv;
            if (RELU) v = fmaxf(v, 0.0f);
            if (OUTBF) ((unsigned short*)outp)[(size_t)(rowb + r) * BN + c] = f2bf(v);
            else       ((float*)outp)[(size_t)(rowb + r) * BN + c] = v;
        }
    }
}

// ---------------- Launch ----------------

extern "C" void kernel_launch(void* const* d_in, const int* in_sizes, int n_in,
                              void* d_out, int out_size, void* d_ws, size_t ws_size,
                              hipStream_t stream) {
    const float* x   = (const float*)d_in[0];
    const int*   ei  = (const int*)d_in[1];
    const float* W1l = (const float*)d_in[2];
    const float* b1  = (const float*)d_in[3];
    const float* W1r = (const float*)d_in[4];
    const float* W2l = (const float*)d_in[5];
    const float* b2  = (const float*)d_in[6];
    const float* W2r = (const float*)d_in[7];
    float* out = (float*)d_out;

    // ws layout (uint units): hb[N*64] aggb[N*64] xb[N*64] Bp1[16384] Bp2[8192]
    //                         col[E] rowptr[N+1] deg[N] cursor[N]
    unsigned* hb    = (unsigned*)d_ws;
    unsigned* aggb  = hb + (size_t)N_NODES * 64;
    unsigned* xb    = aggb + (size_t)N_NODES * 64;
    unsigned* Bp1   = xb + (size_t)N_NODES * 64;
    unsigned* Bp2   = Bp1 + 16384;
    int* col        = (int*)(Bp2 + 8192);
    int* rowptr     = col + E_EDGES;
    int* deg        = rowptr + (N_NODES + 1);
    int* cursor     = deg + N_NODES;

    hipMemsetAsync(deg, 0, (size_t)2 * N_NODES * sizeof(int), stream);  // deg+cursor

    prep<<<5649, 256, 0, stream>>>(ei, deg, x, (uint4*)xb,
                                   W1l, W1r, (uint4*)Bp1, W2l, W2r, (uint4*)Bp2);
    scan_block<<<1, 1024, 0, stream>>>(deg, rowptr, N_NODES, E_EDGES);
    fill_csr<<<2500, 256, 0, stream>>>(ei, rowptr, cursor, col, E_EDGES);

    const int meanBlocks = (N_NODES + 3) / 4;   // 1 wave/node, 4 waves/block
    // Layer 1
    csr_mean_bf<<<meanBlocks, 256, 0, stream>>>((const uint4*)xb, rowptr, col,
                                                (uint4*)aggb, N_NODES);
    {
        int waves = (N_NODES / 16) * 2;
        sage_mfma<128, true, true><<<(waves * 64 + 255) / 256, 256, 0, stream>>>(
            (const unsigned short*)aggb, (const unsigned short*)xb,
            (const unsigned short*)Bp1, b1, hb, N_NODES);
    }
    // Layer 2
    csr_mean_bf<<<meanBlocks, 256, 0, stream>>>((const uint4*)hb, rowptr, col,
                                                (uint4*)aggb, N_NODES);
    {
        int waves = N_NODES / 16;
        sage_mfma<64, false, false><<<(waves * 64 + 255) / 256, 256, 0, stream>>>(
            (const unsigned short*)aggb, (const unsigned short*)hb,
            (const unsigned short*)Bp2, b2, out, N_NODES);
    }
}

// Round 6
// 245.819 us; speedup vs baseline: 1.3421x; 1.3421x over previous
//
#include <hip/hip_runtime.h>
#include <cstddef>

static constexpr int N_NODES = 50000;
static constexpr int E_EDGES = 640000;
static constexpr int F = 128;

typedef __bf16 b8 __attribute__((ext_vector_type(8)));
typedef float  f4 __attribute__((ext_vector_type(4)));

__device__ inline unsigned short f2bf(float f) {           // RTN-even
    unsigned u = __float_as_uint(f);
    u += 0x7FFF + ((u >> 16) & 1);
    return (unsigned short)(u >> 16);
}
__device__ inline float bflo(unsigned u) { return __uint_as_float(u << 16); }
__device__ inline float bfhi(unsigned u) { return __uint_as_float(u & 0xFFFF0000u); }

__device__ inline void acc8(float* s, uint4 u) {
    s[0] += bflo(u.x); s[1] += bfhi(u.x);
    s[2] += bflo(u.y); s[3] += bfhi(u.y);
    s[4] += bflo(u.z); s[5] += bfhi(u.z);
    s[6] += bflo(u.w); s[7] += bfhi(u.w);
}

// ---------------- prep mega-kernel: count_deg | x->bf16 | pack W1 | pack W2 ----------------
template<int BN>
__device__ inline void pack_w_body(int t, const float* __restrict__ Wl,
                                   const float* __restrict__ Wr, uint4* __restrict__ Bp) {
    constexpr int NTg = BN / 16;
    int wid = t >> 6, lane = t & 63;
    if (wid >= 8 * NTg) return;
    int kq = lane >> 4, m = lane & 15;
    int kt = wid / NTg, nt = wid % NTg;
    unsigned short tmp[8];
#pragma unroll
    for (int j = 0; j < 8; ++j) {
        int k = kt * 32 + kq * 8 + j;
        const float* W = (k < 128) ? Wl : Wr;
        tmp[j] = f2bf(W[(size_t)(k & 127) * BN + nt * 16 + m]);
    }
    uint4 u;
    u.x = tmp[0] | ((unsigned)tmp[1] << 16);
    u.y = tmp[2] | ((unsigned)tmp[3] << 16);
    u.z = tmp[4] | ((unsigned)tmp[5] << 16);
    u.w = tmp[6] | ((unsigned)tmp[7] << 16);
    Bp[wid * 64 + lane] = u;
}

__global__ __launch_bounds__(256)
void prep(const int* __restrict__ ei, int* __restrict__ deg,
          const float* __restrict__ x, uint4* __restrict__ xb,
          const float* __restrict__ W1l, const float* __restrict__ W1r, uint4* __restrict__ Bp1,
          const float* __restrict__ W2l, const float* __restrict__ W2r, uint4* __restrict__ Bp2) {
    int b = blockIdx.x, tid = threadIdx.x;
    if (b < 2500) {                       // count_deg (E = 2500*256 exact)
        int e = b * 256 + tid;
        atomicAdd(&deg[ei[E_EDGES + e]], 1);
    } else if (b < 5625) {                // f32 -> bf16 (n8 = 3125*256 exact)
        int i = (b - 2500) * 256 + tid;
        const float4* s = (const float4*)x + (size_t)i * 2;
        float4 v0 = s[0], v1 = s[1];
        uint4 u;
        u.x = f2bf(v0.x) | ((unsigned)f2bf(v0.y) << 16);
        u.y = f2bf(v0.z) | ((unsigned)f2bf(v0.w) << 16);
        u.z = f2bf(v1.x) | ((unsigned)f2bf(v1.y) << 16);
        u.w = f2bf(v1.z) | ((unsigned)f2bf(v1.w) << 16);
        xb[i] = u;
    } else if (b < 5641) {                // pack W1 (64 waves)
        pack_w_body<128>((b - 5625) * 256 + tid, W1l, W1r, Bp1);
    } else {                              // pack W2 (32 waves)
        pack_w_body<64>((b - 5641) * 256 + tid, W2l, W2r, Bp2);
    }
}

// ---------------- hierarchical exclusive scan: deg -> rowptr (3 kernels) ----------------
__global__ void scan_reduce(const int* __restrict__ deg, int* __restrict__ partial, int N) {
    __shared__ int s[256];
    int tid = threadIdx.x;
    int i = blockIdx.x * 256 + tid;
    s[tid] = (i < N) ? deg[i] : 0;
    __syncthreads();
    for (int off = 128; off > 0; off >>= 1) {
        if (tid < off) s[tid] += s[tid + off];
        __syncthreads();
    }
    if (tid == 0) partial[blockIdx.x] = s[0];
}

__global__ void scan_partials(const int* __restrict__ partial, int* __restrict__ poff, int NB) {
    __shared__ int s[256];
    int tid = threadIdx.x;
    int v = (tid < NB) ? partial[tid] : 0;
    s[tid] = v;
    __syncthreads();
    for (int off = 1; off < 256; off <<= 1) {
        int t = (tid >= off) ? s[tid - off] : 0;
        __syncthreads();
        s[tid] += t;
        __syncthreads();
    }
    if (tid < NB) poff[tid] = s[tid] - v;   // exclusive
}

__global__ void scan_final(const int* __restrict__ deg, const int* __restrict__ poff,
                           int* __restrict__ rowptr, int N, int E) {
    __shared__ int s[256];
    int tid = threadIdx.x;
    int i = blockIdx.x * 256 + tid;
    int v = (i < N) ? deg[i] : 0;
    s[tid] = v;
    __syncthreads();
    for (int off = 1; off < 256; off <<= 1) {
        int t = (tid >= off) ? s[tid - off] : 0;
        __syncthreads();
        s[tid] += t;
        __syncthreads();
    }
    if (i < N) rowptr[i] = poff[blockIdx.x] + s[tid] - v;  // exclusive
    if (i == N - 1) rowptr[N] = E;
}

__global__ void fill_csr(const int* __restrict__ ei, const int* __restrict__ rowptr,
                         int* __restrict__ cursor, int* __restrict__ col, int E) {
    int e = blockIdx.x * blockDim.x + threadIdx.x;
    if (e >= E) return;
    int s = ei[e], d = ei[E + e];
    int off = atomicAdd(&cursor[d], 1);
    col[rowptr[d] + off] = s;
}

// ---------------- Mean aggregation: one wave per node, dwordx4 gather ----------------
__global__ __launch_bounds__(256)
void csr_mean_bf(const uint4* __restrict__ feat,
                 const int* __restrict__ rowptr,
                 const int* __restrict__ col,
                 uint4* __restrict__ agg, int N) {
    int wid = (int)((blockIdx.x * 256u + threadIdx.x) >> 6);
    if (wid >= N) return;
    int lane = threadIdx.x & 63;
    int c = lane & 15;     // uint4 chunk within row
    int g = lane >> 4;     // neighbor slot 0..3

    int jb = rowptr[wid], je = rowptr[wid + 1];
    float s0[8] = {0.f, 0.f, 0.f, 0.f, 0.f, 0.f, 0.f, 0.f};
    float s1[8] = {0.f, 0.f, 0.f, 0.f, 0.f, 0.f, 0.f, 0.f};
    for (int j = jb; j < je; j += 8) {
        int i0 = j + g, i1 = j + 4 + g;
        if (i0 < je) {
            uint4 u = feat[(size_t)col[i0] * 16 + c];
            acc8(s0, u);
        }
        if (i1 < je) {
            uint4 u = feat[(size_t)col[i1] * 16 + c];
            acc8(s1, u);
        }
    }
#pragma unroll
    for (int k = 0; k < 8; ++k) s0[k] += s1[k];
#pragma unroll
    for (int k = 0; k < 8; ++k) {
        s0[k] += __shfl_xor(s0[k], 16);
        s0[k] += __shfl_xor(s0[k], 32);
    }
    int d = je - jb;
    float inv = 1.0f / (float)(d > 0 ? d : 1);
    if (g == 0) {
        uint4 o;
        o.x = f2bf(s0[0] * inv) | ((unsigned)f2bf(s0[1] * inv) << 16);
        o.y = f2bf(s0[2] * inv) | ((unsigned)f2bf(s0[3] * inv) << 16);
        o.z = f2bf(s0[4] * inv) | ((unsigned)f2bf(s0[5] * inv) << 16);
        o.w = f2bf(s0[6] * inv) | ((unsigned)f2bf(s0[7] * inv) << 16);
        agg[(size_t)wid * 16 + c] = o;
    }
}

// ---------------- MFMA GEMM: out = [agg|self]@[Wl;Wr] + bias ----------------
template<int BN, bool RELU, bool OUTBF>
__global__ __launch_bounds__(256)
void sage_mfma(const unsigned short* __restrict__ aggb,
               const unsigned short* __restrict__ selfb,
               const unsigned short* __restrict__ Bp,
               const float* __restrict__ bias,
               void* __restrict__ outp, int N) {
    constexpr int NT  = 4;        // col-tiles per wave (64 cols)
    constexpr int NH  = BN / 64;  // col-halves
    constexpr int NTg = BN / 16;
    int gw = (int)((blockIdx.x * 256u + threadIdx.x) >> 6);
    int wt = gw / NH, ch = gw - wt * NH;
    int row0 = wt * 16;
    if (row0 >= N) return;
    int lane = threadIdx.x & 63;
    int m = lane & 15, kq = lane >> 4;

    const unsigned short* arow_a = aggb  + (size_t)(row0 + m) * F + kq * 8;
    const unsigned short* arow_s = selfb + (size_t)(row0 + m) * F + kq * 8;

    f4 zero = {0.f, 0.f, 0.f, 0.f};
    f4 acc[NT] = {zero, zero, zero, zero};

#pragma unroll
    for (int kt = 0; kt < 8; ++kt) {
        const unsigned short* ap = (kt < 4) ? (arow_a + kt * 32) : (arow_s + (kt - 4) * 32);
        b8 a = *((const b8*)ap);
#pragma unroll
        for (int nt = 0; nt < NT; ++nt) {
            b8 b = *((const b8*)(Bp + ((size_t)(kt * NTg + ch * NT + nt) * 64 + lane) * 8));
            acc[nt] = __builtin_amdgcn_mfma_f32_16x16x32_bf16(a, b, acc[nt], 0, 0, 0);
        }
    }

    int rowb = row0 + kq * 4;
#pragma unroll
    for (int nt = 0; nt < NT; ++nt) {
        int c = ch * 64 + nt * 16 + m;
        float bv = bias[c];
#pragma unroll
        for (int r = 0; r < 4; ++r) {
            float v = acc[nt][r] + bv;
            if (RELU) v = fmaxf(v, 0.0f);
            if (OUTBF) ((unsigned short*)outp)[(size_t)(rowb + r) * BN + c] = f2bf(v);
            else       ((float*)outp)[(size_t)(rowb + r) * BN + c] = v;
        }
    }
}

// ---------------- Launch ----------------

extern "C" void kernel_launch(void* const* d_in, const int* in_sizes, int n_in,
                              void* d_out, int out_size, void* d_ws, size_t ws_size,
                              hipStream_t stream) {
    const float* x   = (const float*)d_in[0];
    const int*   ei  = (const int*)d_in[1];
    const float* W1l = (const float*)d_in[2];
    const float* b1  = (const float*)d_in[3];
    const float* W1r = (const float*)d_in[4];
    const float* W2l = (const float*)d_in[5];
    const float* b2  = (const float*)d_in[6];
    const float* W2r = (const float*)d_in[7];
    float* out = (float*)d_out;

    // ws layout (uint units): hb[N*64] aggb[N*64] xb[N*64] Bp1[16384] Bp2[8192]
    //                         col[E] rowptr[N+1] deg[N] cursor[N] partial[256] poff[256]
    unsigned* hb    = (unsigned*)d_ws;
    unsigned* aggb  = hb + (size_t)N_NODES * 64;
    unsigned* xb    = aggb + (size_t)N_NODES * 64;
    unsigned* Bp1   = xb + (size_t)N_NODES * 64;
    unsigned* Bp2   = Bp1 + 16384;
    int* col        = (int*)(Bp2 + 8192);
    int* rowptr     = col + E_EDGES;
    int* deg        = rowptr + (N_NODES + 1);
    int* cursor     = deg + N_NODES;
    int* partial    = cursor + N_NODES;
    int* poff       = partial + 256;

    const int NB = (N_NODES + 255) / 256;   // 196
    hipMemsetAsync(deg, 0, (size_t)2 * N_NODES * sizeof(int), stream);  // deg+cursor

    prep<<<5649, 256, 0, stream>>>(ei, deg, x, (uint4*)xb,
                                   W1l, W1r, (uint4*)Bp1, W2l, W2r, (uint4*)Bp2);
    scan_reduce<<<NB, 256, 0, stream>>>(deg, partial, N_NODES);
    scan_partials<<<1, 256, 0, stream>>>(partial, poff, NB);
    scan_final<<<NB, 256, 0, stream>>>(deg, poff, rowptr, N_NODES, E_EDGES);
    fill_csr<<<2500, 256, 0, stream>>>(ei, rowptr, cursor, col, E_EDGES);

    const int meanBlocks = (N_NODES + 3) / 4;   // 1 wave/node, 4 waves/block
    // Layer 1
    csr_mean_bf<<<meanBlocks, 256, 0, stream>>>((const uint4*)xb, rowptr, col,
                                                (uint4*)aggb, N_NODES);
    {
        int waves = (N_NODES / 16) * 2;
        sage_mfma<128, true, true><<<(waves * 64 + 255) / 256, 256, 0, stream>>>(
            (const unsigned short*)aggb, (const unsigned short*)xb,
            (const unsigned short*)Bp1, b1, hb, N_NODES);
    }
    // Layer 2
    csr_mean_bf<<<meanBlocks, 256, 0, stream>>>((const uint4*)hb, rowptr, col,
                                                (uint4*)aggb, N_NODES);
    {
        int waves = N_NODES / 16;
        sage_mfma<64, false, false><<<(waves * 64 + 255) / 256, 256, 0, stream>>>(
            (const unsigned short*)aggb, (const unsigned short*)hb,
            (const unsigned short*)Bp2, b2, out, N_NODES);
    }
}

// Round 7
// 240.839 us; speedup vs baseline: 1.3699x; 1.0207x over previous
//
#include <hip/hip_runtime.h>
#include <cstddef>

static constexpr int N_NODES = 50000;
static constexpr int E_EDGES = 640000;
static constexpr int F = 128;

typedef __bf16 b8 __attribute__((ext_vector_type(8)));
typedef float  f4 __attribute__((ext_vector_type(4)));

__device__ inline unsigned short f2bf(float f) {           // RTN-even
    unsigned u = __float_as_uint(f);
    u += 0x7FFF + ((u >> 16) & 1);
    return (unsigned short)(u >> 16);
}
__device__ inline float bflo(unsigned u) { return __uint_as_float(u << 16); }
__device__ inline float bfhi(unsigned u) { return __uint_as_float(u & 0xFFFF0000u); }

__device__ inline void acc8(float* s, uint4 u) {
    s[0] += bflo(u.x); s[1] += bfhi(u.x);
    s[2] += bflo(u.y); s[3] += bfhi(u.y);
    s[4] += bflo(u.z); s[5] += bfhi(u.z);
    s[6] += bflo(u.w); s[7] += bfhi(u.w);
}

// ---------------- prep mega-kernel: count_deg | x->bf16 | pack W1 | pack W2 ----------------
template<int BN>
__device__ inline void pack_w_body(int t, const float* __restrict__ Wl,
                                   const float* __restrict__ Wr, uint4* __restrict__ Bp) {
    constexpr int NTg = BN / 16;
    int wid = t >> 6, lane = t & 63;
    if (wid >= 8 * NTg) return;
    int kq = lane >> 4, m = lane & 15;
    int kt = wid / NTg, nt = wid % NTg;
    unsigned short tmp[8];
#pragma unroll
    for (int j = 0; j < 8; ++j) {
        int k = kt * 32 + kq * 8 + j;
        const float* W = (k < 128) ? Wl : Wr;
        tmp[j] = f2bf(W[(size_t)(k & 127) * BN + nt * 16 + m]);
    }
    uint4 u;
    u.x = tmp[0] | ((unsigned)tmp[1] << 16);
    u.y = tmp[2] | ((unsigned)tmp[3] << 16);
    u.z = tmp[4] | ((unsigned)tmp[5] << 16);
    u.w = tmp[6] | ((unsigned)tmp[7] << 16);
    Bp[wid * 64 + lane] = u;
}

__global__ __launch_bounds__(256)
void prep(const int* __restrict__ ei, int* __restrict__ deg,
          const float* __restrict__ x, uint4* __restrict__ xb,
          const float* __restrict__ W1l, const float* __restrict__ W1r, uint4* __restrict__ Bp1,
          const float* __restrict__ W2l, const float* __restrict__ W2r, uint4* __restrict__ Bp2) {
    int b = blockIdx.x, tid = threadIdx.x;
    if (b < 2500) {                       // count_deg (E = 2500*256 exact)
        int e = b * 256 + tid;
        atomicAdd(&deg[ei[E_EDGES + e]], 1);
    } else if (b < 5625) {                // f32 -> bf16 (n8 = 3125*256 exact)
        int i = (b - 2500) * 256 + tid;
        const float4* s = (const float4*)x + (size_t)i * 2;
        float4 v0 = s[0], v1 = s[1];
        uint4 u;
        u.x = f2bf(v0.x) | ((unsigned)f2bf(v0.y) << 16);
        u.y = f2bf(v0.z) | ((unsigned)f2bf(v0.w) << 16);
        u.z = f2bf(v1.x) | ((unsigned)f2bf(v1.y) << 16);
        u.w = f2bf(v1.z) | ((unsigned)f2bf(v1.w) << 16);
        xb[i] = u;
    } else if (b < 5641) {                // pack W1 (64 waves)
        pack_w_body<128>((b - 5625) * 256 + tid, W1l, W1r, Bp1);
    } else {                              // pack W2 (32 waves)
        pack_w_body<64>((b - 5641) * 256 + tid, W2l, W2r, Bp2);
    }
}

// ---------------- hierarchical exclusive scan: deg -> rowptr (3 kernels) ----------------
__global__ void scan_reduce(const int* __restrict__ deg, int* __restrict__ partial, int N) {
    __shared__ int s[256];
    int tid = threadIdx.x;
    int i = blockIdx.x * 256 + tid;
    s[tid] = (i < N) ? deg[i] : 0;
    __syncthreads();
    for (int off = 128; off > 0; off >>= 1) {
        if (tid < off) s[tid] += s[tid + off];
        __syncthreads();
    }
    if (tid == 0) partial[blockIdx.x] = s[0];
}

__global__ void scan_partials(const int* __restrict__ partial, int* __restrict__ poff, int NB) {
    __shared__ int s[256];
    int tid = threadIdx.x;
    int v = (tid < NB) ? partial[tid] : 0;
    s[tid] = v;
    __syncthreads();
    for (int off = 1; off < 256; off <<= 1) {
        int t = (tid >= off) ? s[tid - off] : 0;
        __syncthreads();
        s[tid] += t;
        __syncthreads();
    }
    if (tid < NB) poff[tid] = s[tid] - v;   // exclusive
}

__global__ void scan_final(const int* __restrict__ deg, const int* __restrict__ poff,
                           int* __restrict__ rowptr, int N, int E) {
    __shared__ int s[256];
    int tid = threadIdx.x;
    int i = blockIdx.x * 256 + tid;
    int v = (i < N) ? deg[i] : 0;
    s[tid] = v;
    __syncthreads();
    for (int off = 1; off < 256; off <<= 1) {
        int t = (tid >= off) ? s[tid - off] : 0;
        __syncthreads();
        s[tid] += t;
        __syncthreads();
    }
    if (i < N) rowptr[i] = poff[blockIdx.x] + s[tid] - v;  // exclusive
    if (i == N - 1) rowptr[N] = E;
}

__global__ void fill_csr(const int* __restrict__ ei, const int* __restrict__ rowptr,
                         int* __restrict__ cursor, int* __restrict__ col, int E) {
    int e = blockIdx.x * blockDim.x + threadIdx.x;
    if (e >= E) return;
    int s = ei[e], d = ei[E + e];
    int off = atomicAdd(&cursor[d], 1);
    col[rowptr[d] + off] = s;
}

// ---------------- Fused layer: gather-mean (LDS) + MFMA GEMM ----------------
// Block = 256 threads = 4 waves = 16 nodes. Wave wv gathers nodes wv*4..wv*4+3
// (16 lanes/row dwordx4, 4 slots x4 unroll -> up to 16 rows in flight), mean
// lands in LDS (row stride 272B: A-frag ds_read_b128 is 2-way = free).
// After syncthreads each wave MFMAs its col-slice; self path streams global.
template<int BN, bool RELU, bool OUTBF>
__global__ __launch_bounds__(256)
void sage_layer(const uint4* __restrict__ featv,
                const unsigned short* __restrict__ featb,
                const int* __restrict__ rowptr,
                const int* __restrict__ col,
                const unsigned short* __restrict__ Bp,
                const float* __restrict__ bias,
                void* __restrict__ outp) {
    constexpr int LDW = 68;                 // LDS row stride in dwords (272 B)
    constexpr int NTW = BN / 64;            // col-tiles per wave (2 for 128, 1 for 64)
    constexpr int NTg = BN / 16;
    __shared__ unsigned Alds[16 * LDW];

    const int tid  = threadIdx.x;
    const int wv   = tid >> 6;
    const int lane = tid & 63;
    const int c    = lane & 15;             // uint4 chunk within row
    const int g    = lane >> 4;             // neighbor slot 0..3
    const int node0 = blockIdx.x * 16;

    // ---- gather + mean: 4 nodes per wave ----
#pragma unroll
    for (int i = 0; i < 4; ++i) {
        int node = node0 + wv * 4 + i;
        int jb = rowptr[node], je = rowptr[node + 1];
        float s0[8] = {0.f,0.f,0.f,0.f,0.f,0.f,0.f,0.f};
        float s1[8] = {0.f,0.f,0.f,0.f,0.f,0.f,0.f,0.f};
        float s2[8] = {0.f,0.f,0.f,0.f,0.f,0.f,0.f,0.f};
        float s3[8] = {0.f,0.f,0.f,0.f,0.f,0.f,0.f,0.f};
        for (int j = jb; j < je; j += 16) {
            int i0 = j + g, i1 = j + 4 + g, i2 = j + 8 + g, i3 = j + 12 + g;
            if (i0 < je) { uint4 u = featv[(size_t)col[i0] * 16 + c]; acc8(s0, u); }
            if (i1 < je) { uint4 u = featv[(size_t)col[i1] * 16 + c]; acc8(s1, u); }
            if (i2 < je) { uint4 u = featv[(size_t)col[i2] * 16 + c]; acc8(s2, u); }
            if (i3 < je) { uint4 u = featv[(size_t)col[i3] * 16 + c]; acc8(s3, u); }
        }
#pragma unroll
        for (int k = 0; k < 8; ++k) s0[k] = (s0[k] + s1[k]) + (s2[k] + s3[k]);
#pragma unroll
        for (int k = 0; k < 8; ++k) {
            s0[k] += __shfl_xor(s0[k], 16);
            s0[k] += __shfl_xor(s0[k], 32);
        }
        int d = je - jb;
        float inv = 1.0f / (float)(d > 0 ? d : 1);
        if (g == 0) {
            int r = wv * 4 + i;
            uint4 o;
            o.x = f2bf(s0[0] * inv) | ((unsigned)f2bf(s0[1] * inv) << 16);
            o.y = f2bf(s0[2] * inv) | ((unsigned)f2bf(s0[3] * inv) << 16);
            o.z = f2bf(s0[4] * inv) | ((unsigned)f2bf(s0[5] * inv) << 16);
            o.w = f2bf(s0[6] * inv) | ((unsigned)f2bf(s0[7] * inv) << 16);
            *((uint4*)&Alds[r * LDW + c * 4]) = o;
        }
    }
    __syncthreads();

    // ---- MFMA: wave wv computes col-tiles nt = wv*NTW .. +NTW-1 ----
    const int m  = lane & 15;
    const int kq = lane >> 4;
    const unsigned short* srow = featb + (size_t)(node0 + m) * F + kq * 8;

    f4 zero = {0.f, 0.f, 0.f, 0.f};
    f4 acc[NTW];
#pragma unroll
    for (int t = 0; t < NTW; ++t) acc[t] = zero;

#pragma unroll
    for (int kt = 0; kt < 8; ++kt) {
        b8 a;
        if (kt < 4) {
            a = *((const b8*)((const char*)Alds + m * 272 + kt * 64 + kq * 16));
        } else {
            a = *((const b8*)(srow + (kt - 4) * 32));
        }
#pragma unroll
        for (int t = 0; t < NTW; ++t) {
            int nt = wv * NTW + t;
            b8 b = *((const b8*)(Bp + ((size_t)(kt * NTg + nt) * 64 + lane) * 8));
            acc[t] = __builtin_amdgcn_mfma_f32_16x16x32_bf16(a, b, acc[t], 0, 0, 0);
        }
    }

    // ---- epilogue ----
    int rowb = node0 + kq * 4;
#pragma unroll
    for (int t = 0; t < NTW; ++t) {
        int cc = (wv * NTW + t) * 16 + m;
        float bv = bias[cc];
#pragma unroll
        for (int r = 0; r < 4; ++r) {
            float v = acc[t][r] + bv;
            if (RELU) v = fmaxf(v, 0.0f);
            if (OUTBF) ((unsigned short*)outp)[(size_t)(rowb + r) * BN + cc] = f2bf(v);
            else       ((float*)outp)[(size_t)(rowb + r) * BN + cc] = v;
        }
    }
}

// ---------------- Launch ----------------

extern "C" void kernel_launch(void* const* d_in, const int* in_sizes, int n_in,
                              void* d_out, int out_size, void* d_ws, size_t ws_size,
                              hipStream_t stream) {
    const float* x   = (const float*)d_in[0];
    const int*   ei  = (const int*)d_in[1];
    const float* W1l = (const float*)d_in[2];
    const float* b1  = (const float*)d_in[3];
    const float* W1r = (const float*)d_in[4];
    const float* W2l = (const float*)d_in[5];
    const float* b2  = (const float*)d_in[6];
    const float* W2r = (const float*)d_in[7];
    float* out = (float*)d_out;

    // ws layout (uint units): hb[N*64] xb[N*64] Bp1[16384] Bp2[8192]
    //                         col[E] rowptr[N+1] deg[N] cursor[N] partial[256] poff[256]
    unsigned* hb    = (unsigned*)d_ws;
    unsigned* xb    = hb + (size_t)N_NODES * 64;
    unsigned* Bp1   = xb + (size_t)N_NODES * 64;
    unsigned* Bp2   = Bp1 + 16384;
    int* col        = (int*)(Bp2 + 8192);
    int* rowptr     = col + E_EDGES;
    int* deg        = rowptr + (N_NODES + 1);
    int* cursor     = deg + N_NODES;
    int* partial    = cursor + N_NODES;
    int* poff       = partial + 256;

    const int NB = (N_NODES + 255) / 256;   // 196
    hipMemsetAsync(deg, 0, (size_t)2 * N_NODES * sizeof(int), stream);  // deg+cursor

    prep<<<5649, 256, 0, stream>>>(ei, deg, x, (uint4*)xb,
                                   W1l, W1r, (uint4*)Bp1, W2l, W2r, (uint4*)Bp2);
    scan_reduce<<<NB, 256, 0, stream>>>(deg, partial, N_NODES);
    scan_partials<<<1, 256, 0, stream>>>(partial, poff, NB);
    scan_final<<<NB, 256, 0, stream>>>(deg, poff, rowptr, N_NODES, E_EDGES);
    fill_csr<<<2500, 256, 0, stream>>>(ei, rowptr, cursor, col, E_EDGES);

    const int layerBlocks = N_NODES / 16;   // 3125, exact
    sage_layer<128, true, true><<<layerBlocks, 256, 0, stream>>>(
        (const uint4*)xb, (const unsigned short*)xb, rowptr, col,
        (const unsigned short*)Bp1, b1, hb);
    sage_layer<64, false, false><<<layerBlocks, 256, 0, stream>>>(
        (const uint4*)hb, (const unsigned short*)hb, rowptr, col,
        (const unsigned short*)Bp2, b2, out);
}

// Round 8
// 231.565 us; speedup vs baseline: 1.4247x; 1.0400x over previous
//
#include <hip/hip_runtime.h>
#include <cstddef>

static constexpr int N_NODES = 50000;
static constexpr int E_EDGES = 640000;
static constexpr int F = 128;

typedef __bf16 b8 __attribute__((ext_vector_type(8)));
typedef float  f4 __attribute__((ext_vector_type(4)));

__device__ inline unsigned short f2bf(float f) {           // RTN-even
    unsigned u = __float_as_uint(f);
    u += 0x7FFF + ((u >> 16) & 1);
    return (unsigned short)(u >> 16);
}
__device__ inline float bflo(unsigned u) { return __uint_as_float(u << 16); }
__device__ inline float bfhi(unsigned u) { return __uint_as_float(u & 0xFFFF0000u); }

__device__ inline void acc8(float* s, uint4 u) {
    s[0] += bflo(u.x); s[1] += bfhi(u.x);
    s[2] += bflo(u.y); s[3] += bfhi(u.y);
    s[4] += bflo(u.z); s[5] += bfhi(u.z);
    s[6] += bflo(u.w); s[7] += bfhi(u.w);
}

// ---------------- prep mega-kernel: count_deg | x->bf16 | pack W1 | pack W2 ----------------
template<int BN>
__device__ inline void pack_w_body(int t, const float* __restrict__ Wl,
                                   const float* __restrict__ Wr, uint4* __restrict__ Bp) {
    constexpr int NTg = BN / 16;
    int wid = t >> 6, lane = t & 63;
    if (wid >= 8 * NTg) return;
    int kq = lane >> 4, m = lane & 15;
    int kt = wid / NTg, nt = wid % NTg;
    unsigned short tmp[8];
#pragma unroll
    for (int j = 0; j < 8; ++j) {
        int k = kt * 32 + kq * 8 + j;
        const float* W = (k < 128) ? Wl : Wr;
        tmp[j] = f2bf(W[(size_t)(k & 127) * BN + nt * 16 + m]);
    }
    uint4 u;
    u.x = tmp[0] | ((unsigned)tmp[1] << 16);
    u.y = tmp[2] | ((unsigned)tmp[3] << 16);
    u.z = tmp[4] | ((unsigned)tmp[5] << 16);
    u.w = tmp[6] | ((unsigned)tmp[7] << 16);
    Bp[wid * 64 + lane] = u;
}

__global__ __launch_bounds__(256)
void prep(const int* __restrict__ ei, int* __restrict__ deg,
          const float* __restrict__ x, uint4* __restrict__ xb,
          const float* __restrict__ W1l, const float* __restrict__ W1r, uint4* __restrict__ Bp1,
          const float* __restrict__ W2l, const float* __restrict__ W2r, uint4* __restrict__ Bp2) {
    int b = blockIdx.x, tid = threadIdx.x;
    if (b < 2500) {                       // count_deg (E = 2500*256 exact)
        int e = b * 256 + tid;
        atomicAdd(&deg[ei[E_EDGES + e]], 1);
    } else if (b < 5625) {                // f32 -> bf16 (n8 = 3125*256 exact)
        int i = (b - 2500) * 256 + tid;
        const float4* s = (const float4*)x + (size_t)i * 2;
        float4 v0 = s[0], v1 = s[1];
        uint4 u;
        u.x = f2bf(v0.x) | ((unsigned)f2bf(v0.y) << 16);
        u.y = f2bf(v0.z) | ((unsigned)f2bf(v0.w) << 16);
        u.z = f2bf(v1.x) | ((unsigned)f2bf(v1.y) << 16);
        u.w = f2bf(v1.z) | ((unsigned)f2bf(v1.w) << 16);
        xb[i] = u;
    } else if (b < 5641) {                // pack W1 (64 waves)
        pack_w_body<128>((b - 5625) * 256 + tid, W1l, W1r, Bp1);
    } else {                              // pack W2 (32 waves)
        pack_w_body<64>((b - 5641) * 256 + tid, W2l, W2r, Bp2);
    }
}

// ---------------- hierarchical exclusive scan: deg -> rowptr (3 kernels) ----------------
__global__ void scan_reduce(const int* __restrict__ deg, int* __restrict__ partial, int N) {
    __shared__ int s[256];
    int tid = threadIdx.x;
    int i = blockIdx.x * 256 + tid;
    s[tid] = (i < N) ? deg[i] : 0;
    __syncthreads();
    for (int off = 128; off > 0; off >>= 1) {
        if (tid < off) s[tid] += s[tid + off];
        __syncthreads();
    }
    if (tid == 0) partial[blockIdx.x] = s[0];
}

__global__ void scan_partials(const int* __restrict__ partial, int* __restrict__ poff, int NB) {
    __shared__ int s[256];
    int tid = threadIdx.x;
    int v = (tid < NB) ? partial[tid] : 0;
    s[tid] = v;
    __syncthreads();
    for (int off = 1; off < 256; off <<= 1) {
        int t = (tid >= off) ? s[tid - off] : 0;
        __syncthreads();
        s[tid] += t;
        __syncthreads();
    }
    if (tid < NB) poff[tid] = s[tid] - v;   // exclusive
}

__global__ void scan_final(const int* __restrict__ deg, const int* __restrict__ poff,
                           int* __restrict__ rowptr, int N, int E) {
    __shared__ int s[256];
    int tid = threadIdx.x;
    int i = blockIdx.x * 256 + tid;
    int v = (i < N) ? deg[i] : 0;
    s[tid] = v;
    __syncthreads();
    for (int off = 1; off < 256; off <<= 1) {
        int t = (tid >= off) ? s[tid - off] : 0;
        __syncthreads();
        s[tid] += t;
        __syncthreads();
    }
    if (i < N) rowptr[i] = poff[blockIdx.x] + s[tid] - v;  // exclusive
    if (i == N - 1) rowptr[N] = E;
}

__global__ void fill_csr(const int* __restrict__ ei, const int* __restrict__ rowptr,
                         int* __restrict__ cursor, int* __restrict__ col, int E) {
    int e = blockIdx.x * blockDim.x + threadIdx.x;
    if (e >= E) return;
    int s = ei[e], d = ei[E + e];
    int off = atomicAdd(&cursor[d], 1);
    col[rowptr[d] + off] = s;
}

// ---------------- Fused layer: gather-mean (LDS) + MFMA GEMM ----------------
// Block = 256 threads = 4 waves = 16 nodes. Each 16-lane GROUP owns one node:
// lane c accumulates uint4-chunk c of the row across the node's neighbor list
// (4-deep unroll -> 16 loads in flight per wave; all 4 nodes concurrent; NO
// cross-lane reduce). Result packs straight to LDS (row stride 272 B).
// After syncthreads each wave MFMAs its col-slice; self path streams global.
template<int BN, bool RELU, bool OUTBF>
__global__ __launch_bounds__(256)
void sage_layer(const uint4* __restrict__ featv,
                const unsigned short* __restrict__ featb,
                const int* __restrict__ rowptr,
                const int* __restrict__ col,
                const unsigned short* __restrict__ Bp,
                const float* __restrict__ bias,
                void* __restrict__ outp) {
    constexpr int LDW = 68;                 // LDS row stride in dwords (272 B)
    constexpr int NTW = BN / 64;            // col-tiles per wave (2 for 128, 1 for 64)
    constexpr int NTg = BN / 16;
    __shared__ unsigned Alds[16 * LDW];

    const int tid  = threadIdx.x;
    const int wv   = tid >> 6;
    const int lane = tid & 63;
    const int c    = lane & 15;             // uint4 chunk within row
    const int g    = lane >> 4;             // node-slot within wave (0..3)
    const int node0 = blockIdx.x * 16;
    const int node  = node0 + wv * 4 + g;   // this group's node

    // ---- gather + mean: one node per 16-lane group ----
    {
        int jb = rowptr[node], je = rowptr[node + 1];
        float s0[8] = {0.f,0.f,0.f,0.f,0.f,0.f,0.f,0.f};
        float s1[8] = {0.f,0.f,0.f,0.f,0.f,0.f,0.f,0.f};
        float s2[8] = {0.f,0.f,0.f,0.f,0.f,0.f,0.f,0.f};
        float s3[8] = {0.f,0.f,0.f,0.f,0.f,0.f,0.f,0.f};
        int j = jb;
        for (; j + 3 < je; j += 4) {
            uint4 u0 = featv[(size_t)col[j + 0] * 16 + c];
            uint4 u1 = featv[(size_t)col[j + 1] * 16 + c];
            uint4 u2 = featv[(size_t)col[j + 2] * 16 + c];
            uint4 u3 = featv[(size_t)col[j + 3] * 16 + c];
            acc8(s0, u0); acc8(s1, u1); acc8(s2, u2); acc8(s3, u3);
        }
        for (; j < je; ++j) {
            uint4 u0 = featv[(size_t)col[j] * 16 + c];
            acc8(s0, u0);
        }
        int d = je - jb;
        float inv = 1.0f / (float)(d > 0 ? d : 1);
        float r[8];
#pragma unroll
        for (int k = 0; k < 8; ++k) r[k] = ((s0[k] + s1[k]) + (s2[k] + s3[k])) * inv;
        uint4 o;
        o.x = f2bf(r[0]) | ((unsigned)f2bf(r[1]) << 16);
        o.y = f2bf(r[2]) | ((unsigned)f2bf(r[3]) << 16);
        o.z = f2bf(r[4]) | ((unsigned)f2bf(r[5]) << 16);
        o.w = f2bf(r[6]) | ((unsigned)f2bf(r[7]) << 16);
        *((uint4*)&Alds[(wv * 4 + g) * LDW + c * 4]) = o;
    }
    __syncthreads();

    // ---- MFMA: wave wv computes col-tiles nt = wv*NTW .. +NTW-1 ----
    const int m  = lane & 15;
    const int kq = lane >> 4;
    const unsigned short* srow = featb + (size_t)(node0 + m) * F + kq * 8;

    f4 zero = {0.f, 0.f, 0.f, 0.f};
    f4 acc[NTW];
#pragma unroll
    for (int t = 0; t < NTW; ++t) acc[t] = zero;

#pragma unroll
    for (int kt = 0; kt < 8; ++kt) {
        b8 a;
        if (kt < 4) {
            a = *((const b8*)((const char*)Alds + m * 272 + kt * 64 + kq * 16));
        } else {
            a = *((const b8*)(srow + (kt - 4) * 32));
        }
#pragma unroll
        for (int t = 0; t < NTW; ++t) {
            int nt = wv * NTW + t;
            b8 b = *((const b8*)(Bp + ((size_t)(kt * NTg + nt) * 64 + lane) * 8));
            acc[t] = __builtin_amdgcn_mfma_f32_16x16x32_bf16(a, b, acc[t], 0, 0, 0);
        }
    }

    // ---- epilogue ----
    int rowb = node0 + kq * 4;
#pragma unroll
    for (int t = 0; t < NTW; ++t) {
        int cc = (wv * NTW + t) * 16 + m;
        float bv = bias[cc];
#pragma unroll
        for (int r = 0; r < 4; ++r) {
            float v = acc[t][r] + bv;
            if (RELU) v = fmaxf(v, 0.0f);
            if (OUTBF) ((unsigned short*)outp)[(size_t)(rowb + r) * BN + cc] = f2bf(v);
            else       ((float*)outp)[(size_t)(rowb + r) * BN + cc] = v;
        }
    }
}

// ---------------- Launch ----------------

extern "C" void kernel_launch(void* const* d_in, const int* in_sizes, int n_in,
                              void* d_out, int out_size, void* d_ws, size_t ws_size,
                              hipStream_t stream) {
    const float* x   = (const float*)d_in[0];
    const int*   ei  = (const int*)d_in[1];
    const float* W1l = (const float*)d_in[2];
    const float* b1  = (const float*)d_in[3];
    const float* W1r = (const float*)d_in[4];
    const float* W2l = (const float*)d_in[5];
    const float* b2  = (const float*)d_in[6];
    const float* W2r = (const float*)d_in[7];
    float* out = (float*)d_out;

    // ws layout (uint units): hb[N*64] xb[N*64] Bp1[16384] Bp2[8192]
    //                         col[E] rowptr[N+1] deg[N] cursor[N] partial[256] poff[256]
    unsigned* hb    = (unsigned*)d_ws;
    unsigned* xb    = hb + (size_t)N_NODES * 64;
    unsigned* Bp1   = xb + (size_t)N_NODES * 64;
    unsigned* Bp2   = Bp1 + 16384;
    int* col        = (int*)(Bp2 + 8192);
    int* rowptr     = col + E_EDGES;
    int* deg        = rowptr + (N_NODES + 1);
    int* cursor     = deg + N_NODES;
    int* partial    = cursor + N_NODES;
    int* poff       = partial + 256;

    const int NB = (N_NODES + 255) / 256;   // 196
    hipMemsetAsync(deg, 0, (size_t)2 * N_NODES * sizeof(int), stream);  // deg+cursor

    prep<<<5649, 256, 0, stream>>>(ei, deg, x, (uint4*)xb,
                                   W1l, W1r, (uint4*)Bp1, W2l, W2r, (uint4*)Bp2);
    scan_reduce<<<NB, 256, 0, stream>>>(deg, partial, N_NODES);
    scan_partials<<<1, 256, 0, stream>>>(partial, poff, NB);
    scan_final<<<NB, 256, 0, stream>>>(deg, poff, rowptr, N_NODES, E_EDGES);
    fill_csr<<<2500, 256, 0, stream>>>(ei, rowptr, cursor, col, E_EDGES);

    const int layerBlocks = N_NODES / 16;   // 3125, exact
    sage_layer<128, true, true><<<layerBlocks, 256, 0, stream>>>(
        (const uint4*)xb, (const unsigned short*)xb, rowptr, col,
        (const unsigned short*)Bp1, b1, hb);
    sage_layer<64, false, false><<<layerBlocks, 256, 0, stream>>>(
        (const uint4*)hb, (const unsigned short*)hb, rowptr, col,
        (const unsigned short*)Bp2, b2, out);
}

// Round 9
// 217.434 us; speedup vs baseline: 1.5173x; 1.0650x over previous
//
#include <hip/hip_runtime.h>
#include <cstddef>

static constexpr int N_NODES = 50000;
static constexpr int E_EDGES = 640000;
static constexpr int F = 128;

typedef __bf16 b8 __attribute__((ext_vector_type(8)));
typedef float  f4 __attribute__((ext_vector_type(4)));

__device__ inline unsigned short f2bf(float f) {           // RTN-even
    unsigned u = __float_as_uint(f);
    u += 0x7FFF + ((u >> 16) & 1);
    return (unsigned short)(u >> 16);
}
__device__ inline float bflo(unsigned u) { return __uint_as_float(u << 16); }
__device__ inline float bfhi(unsigned u) { return __uint_as_float(u & 0xFFFF0000u); }

__device__ inline void acc8(float* s, uint4 u) {
    s[0] += bflo(u.x); s[1] += bfhi(u.x);
    s[2] += bflo(u.y); s[3] += bfhi(u.y);
    s[4] += bflo(u.z); s[5] += bfhi(u.z);
    s[6] += bflo(u.w); s[7] += bfhi(u.w);
}

// ---------------- prep mega-kernel: count_deg | x->bf16 | pack W1 | pack W2 ----------------
template<int BN>
__device__ inline void pack_w_body(int t, const float* __restrict__ Wl,
                                   const float* __restrict__ Wr, uint4* __restrict__ Bp) {
    constexpr int NTg = BN / 16;
    int wid = t >> 6, lane = t & 63;
    if (wid >= 8 * NTg) return;
    int kq = lane >> 4, m = lane & 15;
    int kt = wid / NTg, nt = wid % NTg;
    unsigned short tmp[8];
#pragma unroll
    for (int j = 0; j < 8; ++j) {
        int k = kt * 32 + kq * 8 + j;
        const float* W = (k < 128) ? Wl : Wr;
        tmp[j] = f2bf(W[(size_t)(k & 127) * BN + nt * 16 + m]);
    }
    uint4 u;
    u.x = tmp[0] | ((unsigned)tmp[1] << 16);
    u.y = tmp[2] | ((unsigned)tmp[3] << 16);
    u.z = tmp[4] | ((unsigned)tmp[5] << 16);
    u.w = tmp[6] | ((unsigned)tmp[7] << 16);
    Bp[wid * 64 + lane] = u;
}

__global__ __launch_bounds__(256)
void prep(const int* __restrict__ ei, int* __restrict__ deg,
          const float* __restrict__ x, uint4* __restrict__ xb,
          const float* __restrict__ W1l, const float* __restrict__ W1r, uint4* __restrict__ Bp1,
          const float* __restrict__ W2l, const float* __restrict__ W2r, uint4* __restrict__ Bp2) {
    int b = blockIdx.x, tid = threadIdx.x;
    if (b < 2500) {                       // count_deg (E = 2500*256 exact)
        int e = b * 256 + tid;
        atomicAdd(&deg[ei[E_EDGES + e]], 1);
    } else if (b < 5625) {                // f32 -> bf16 (n8 = 3125*256 exact)
        int i = (b - 2500) * 256 + tid;
        const float4* s = (const float4*)x + (size_t)i * 2;
        float4 v0 = s[0], v1 = s[1];
        uint4 u;
        u.x = f2bf(v0.x) | ((unsigned)f2bf(v0.y) << 16);
        u.y = f2bf(v0.z) | ((unsigned)f2bf(v0.w) << 16);
        u.z = f2bf(v1.x) | ((unsigned)f2bf(v1.y) << 16);
        u.w = f2bf(v1.z) | ((unsigned)f2bf(v1.w) << 16);
        xb[i] = u;
    } else if (b < 5641) {                // pack W1 (64 waves)
        pack_w_body<128>((b - 5625) * 256 + tid, W1l, W1r, Bp1);
    } else {                              // pack W2 (32 waves)
        pack_w_body<64>((b - 5641) * 256 + tid, W2l, W2r, Bp2);
    }
}

// ---------------- scan (2 kernels): reduce, then fused partials+final ----------------
__global__ void scan_reduce(const int* __restrict__ deg, int* __restrict__ partial, int N) {
    __shared__ int s[256];
    int tid = threadIdx.x;
    int i = blockIdx.x * 256 + tid;
    s[tid] = (i < N) ? deg[i] : 0;
    __syncthreads();
    for (int off = 128; off > 0; off >>= 1) {
        if (tid < off) s[tid] += s[tid + off];
        __syncthreads();
    }
    if (tid == 0) partial[blockIdx.x] = s[0];
}

__global__ void scan_final2(const int* __restrict__ deg, const int* __restrict__ partial,
                            int* __restrict__ rowptr, int N, int E, int NB) {
    __shared__ int p[256];
    __shared__ int poffb;
    int tid = threadIdx.x;
    // every block scans the partial array locally (NB=196, cheap)
    int pv = (tid < NB) ? partial[tid] : 0;
    p[tid] = pv;
    __syncthreads();
    for (int off = 1; off < 256; off <<= 1) {
        int t = (tid >= off) ? p[tid - off] : 0;
        __syncthreads();
        p[tid] += t;
        __syncthreads();
    }
    if (tid == 0) poffb = p[blockIdx.x] - partial[blockIdx.x];   // exclusive
    __syncthreads();
    // per-block exclusive scan of deg
    int i = blockIdx.x * 256 + tid;
    int v = (i < N) ? deg[i] : 0;
    p[tid] = v;
    __syncthreads();
    for (int off = 1; off < 256; off <<= 1) {
        int t = (tid >= off) ? p[tid - off] : 0;
        __syncthreads();
        p[tid] += t;
        __syncthreads();
    }
    if (i < N) rowptr[i] = poffb + p[tid] - v;
    if (i == N - 1) rowptr[N] = E;
}

__global__ void fill_csr(const int* __restrict__ ei, const int* __restrict__ rowptr,
                         int* __restrict__ cursor, int* __restrict__ col, int E) {
    int e = blockIdx.x * blockDim.x + threadIdx.x;
    if (e >= E) return;
    int s = ei[e], d = ei[E + e];
    int off = atomicAdd(&cursor[d], 1);
    col[rowptr[d] + off] = s;
}

// ---------------- Fused L1 + L2-projections ----------------
// Block = 256 threads = 4 waves = 16 nodes.
// Phase 1: gather-mean of x into Alds (16-lane group per node, no cross-lane).
// Phase 2: h = relu([agg|self]@[W1l;W1r] + b1) -> staged bf16 in Hlds.
// Phase 3: Z = h@W2l (bf16 -> Zb),  S = h@W2r + b2 (f32 -> out).
// Final out is completed by gather_add (out += mean_agg(Z)).
__global__ __launch_bounds__(256)
void sage_l1(const uint4* __restrict__ featv,
             const unsigned short* __restrict__ featb,
             const int* __restrict__ rowptr,
             const int* __restrict__ col,
             const unsigned short* __restrict__ Bp1,
             const unsigned short* __restrict__ Bp2,
             const float* __restrict__ b1,
             const float* __restrict__ b2,
             unsigned short* __restrict__ Zb,
             float* __restrict__ out) {
    constexpr int LDW = 68;                    // Alds row stride (dwords) = 272 B
    __shared__ unsigned Alds[16 * LDW];
    __shared__ unsigned short Hlds[16 * 136];  // h tile, stride 136 shorts = 272 B

    const int tid  = threadIdx.x;
    const int wv   = tid >> 6;
    const int lane = tid & 63;
    const int c    = lane & 15;                // uint4 chunk within row
    const int g    = lane >> 4;                // node-slot within wave (0..3)
    const int node0 = blockIdx.x * 16;
    const int node  = node0 + wv * 4 + g;

    // ---- Phase 1: gather + mean (one node per 16-lane group) ----
    {
        int jb = rowptr[node], je = rowptr[node + 1];
        float s0[8] = {0.f,0.f,0.f,0.f,0.f,0.f,0.f,0.f};
        float s1[8] = {0.f,0.f,0.f,0.f,0.f,0.f,0.f,0.f};
        float s2[8] = {0.f,0.f,0.f,0.f,0.f,0.f,0.f,0.f};
        float s3[8] = {0.f,0.f,0.f,0.f,0.f,0.f,0.f,0.f};
        int j = jb;
        for (; j + 3 < je; j += 4) {
            uint4 u0 = featv[(size_t)col[j + 0] * 16 + c];
            uint4 u1 = featv[(size_t)col[j + 1] * 16 + c];
            uint4 u2 = featv[(size_t)col[j + 2] * 16 + c];
            uint4 u3 = featv[(size_t)col[j + 3] * 16 + c];
            acc8(s0, u0); acc8(s1, u1); acc8(s2, u2); acc8(s3, u3);
        }
        for (; j < je; ++j) {
            uint4 u0 = featv[(size_t)col[j] * 16 + c];
            acc8(s0, u0);
        }
        int d = je - jb;
        float inv = 1.0f / (float)(d > 0 ? d : 1);
        float r[8];
#pragma unroll
        for (int k = 0; k < 8; ++k) r[k] = ((s0[k] + s1[k]) + (s2[k] + s3[k])) * inv;
        uint4 o;
        o.x = f2bf(r[0]) | ((unsigned)f2bf(r[1]) << 16);
        o.y = f2bf(r[2]) | ((unsigned)f2bf(r[3]) << 16);
        o.z = f2bf(r[4]) | ((unsigned)f2bf(r[5]) << 16);
        o.w = f2bf(r[6]) | ((unsigned)f2bf(r[7]) << 16);
        *((uint4*)&Alds[(wv * 4 + g) * LDW + c * 4]) = o;
    }
    __syncthreads();

    // ---- Phase 2: L1 MFMA, h -> Hlds ----
    const int m  = lane & 15;
    const int kq = lane >> 4;
    const unsigned short* srow = featb + (size_t)(node0 + m) * F + kq * 8;

    f4 zero = {0.f, 0.f, 0.f, 0.f};
    f4 acc[2] = {zero, zero};
#pragma unroll
    for (int kt = 0; kt < 8; ++kt) {
        b8 a;
        if (kt < 4) a = *((const b8*)((const char*)Alds + m * 272 + kt * 64 + kq * 16));
        else        a = *((const b8*)(srow + (kt - 4) * 32));
#pragma unroll
        for (int t = 0; t < 2; ++t) {
            int nt = wv * 2 + t;
            b8 b = *((const b8*)(Bp1 + ((size_t)(kt * 8 + nt) * 64 + lane) * 8));
            acc[t] = __builtin_amdgcn_mfma_f32_16x16x32_bf16(a, b, acc[t], 0, 0, 0);
        }
    }
    {
        int rowb = kq * 4;
#pragma unroll
        for (int t = 0; t < 2; ++t) {
            int cc = (wv * 2 + t) * 16 + m;
            float bv = b1[cc];
#pragma unroll
            for (int r = 0; r < 4; ++r) {
                float v = fmaxf(acc[t][r] + bv, 0.0f);
                Hlds[(rowb + r) * 136 + cc] = f2bf(v);
            }
        }
    }
    __syncthreads();

    // ---- Phase 3: Z = h@W2l (bf16), S = h@W2r + b2 (f32 -> out) ----
    f4 accZ = zero, accS = zero;
#pragma unroll
    for (int kt = 0; kt < 4; ++kt) {
        b8 a = *((const b8*)((const char*)Hlds + m * 272 + kt * 64 + kq * 16));
        b8 bz = *((const b8*)(Bp2 + ((size_t)(kt * 4 + wv) * 64 + lane) * 8));
        b8 bs = *((const b8*)(Bp2 + ((size_t)((kt + 4) * 4 + wv) * 64 + lane) * 8));
        accZ = __builtin_amdgcn_mfma_f32_16x16x32_bf16(a, bz, accZ, 0, 0, 0);
        accS = __builtin_amdgcn_mfma_f32_16x16x32_bf16(a, bs, accS, 0, 0, 0);
    }
    {
        int rowg = node0 + kq * 4;
        int cc = wv * 16 + m;
        float bv = b2[cc];
#pragma unroll
        for (int r = 0; r < 4; ++r) {
            Zb[(size_t)(rowg + r) * 64 + cc] = f2bf(accZ[r]);
            out[(size_t)(rowg + r) * 64 + cc] = accS[r] + bv;
        }
    }
}

// ---------------- Layer-2 gather: out += mean_agg(Z) ----------------
// Z rows = 64 bf16 = 128 B = 8 uint4. 8 lanes per node; 4-deep volley
// -> 32 loads in flight per wave; f32 read-modify-write into out.
__global__ __launch_bounds__(256)
void gather_add(const uint4* __restrict__ Zv,
                const int* __restrict__ rowptr,
                const int* __restrict__ col,
                float* __restrict__ out, int N) {
    int t = blockIdx.x * 256 + threadIdx.x;
    int node = t >> 3;
    if (node >= N) return;
    int c = t & 7;                        // uint4 chunk within Z row

    int jb = rowptr[node], je = rowptr[node + 1];
    float s0[8] = {0.f,0.f,0.f,0.f,0.f,0.f,0.f,0.f};
    float s1[8] = {0.f,0.f,0.f,0.f,0.f,0.f,0.f,0.f};
    float s2[8] = {0.f,0.f,0.f,0.f,0.f,0.f,0.f,0.f};
    float s3[8] = {0.f,0.f,0.f,0.f,0.f,0.f,0.f,0.f};
    int j = jb;
    for (; j + 3 < je; j += 4) {
        uint4 u0 = Zv[(size_t)col[j + 0] * 8 + c];
        uint4 u1 = Zv[(size_t)col[j + 1] * 8 + c];
        uint4 u2 = Zv[(size_t)col[j + 2] * 8 + c];
        uint4 u3 = Zv[(size_t)col[j + 3] * 8 + c];
        acc8(s0, u0); acc8(s1, u1); acc8(s2, u2); acc8(s3, u3);
    }
    for (; j < je; ++j) {
        uint4 u0 = Zv[(size_t)col[j] * 8 + c];
        acc8(s0, u0);
    }
    int d = je - jb;
    float inv = 1.0f / (float)(d > 0 ? d : 1);
    float* op = out + (size_t)node * 64 + c * 8;
    float4 o0 = *((float4*)op);
    float4 o1 = *((float4*)(op + 4));
    o0.x += ((s0[0] + s1[0]) + (s2[0] + s3[0])) * inv;
    o0.y += ((s0[1] + s1[1]) + (s2[1] + s3[1])) * inv;
    o0.z += ((s0[2] + s1[2]) + (s2[2] + s3[2])) * inv;
    o0.w += ((s0[3] + s1[3]) + (s2[3] + s3[3])) * inv;
    o1.x += ((s0[4] + s1[4]) + (s2[4] + s3[4])) * inv;
    o1.y += ((s0[5] + s1[5]) + (s2[5] + s3[5])) * inv;
    o1.z += ((s0[6] + s1[6]) + (s2[6] + s3[6])) * inv;
    o1.w += ((s0[7] + s1[7]) + (s2[7] + s3[7])) * inv;
    *((float4*)op) = o0;
    *((float4*)(op + 4)) = o1;
}

// ---------------- Launch ----------------

extern "C" void kernel_launch(void* const* d_in, const int* in_sizes, int n_in,
                              void* d_out, int out_size, void* d_ws, size_t ws_size,
                              hipStream_t stream) {
    const float* x   = (const float*)d_in[0];
    const int*   ei  = (const int*)d_in[1];
    const float* W1l = (const float*)d_in[2];
    const float* b1  = (const float*)d_in[3];
    const float* W1r = (const float*)d_in[4];
    const float* W2l = (const float*)d_in[5];
    const float* b2  = (const float*)d_in[6];
    const float* W2r = (const float*)d_in[7];
    float* out = (float*)d_out;

    // ws layout (uint units): Zb[N*32] xb[N*64] Bp1[16384] Bp2[8192]
    //                         col[E] rowptr[N+1] deg[N] cursor[N] partial[256]
    unsigned* Zb    = (unsigned*)d_ws;
    unsigned* xb    = Zb + (size_t)N_NODES * 32;
    unsigned* Bp1   = xb + (size_t)N_NODES * 64;
    unsigned* Bp2   = Bp1 + 16384;
    int* col        = (int*)(Bp2 + 8192);
    int* rowptr     = col + E_EDGES;
    int* deg        = rowptr + (N_NODES + 1);
    int* cursor     = deg + N_NODES;
    int* partial    = cursor + N_NODES;

    const int NB = (N_NODES + 255) / 256;   // 196
    hipMemsetAsync(deg, 0, (size_t)2 * N_NODES * sizeof(int), stream);  // deg+cursor

    prep<<<5649, 256, 0, stream>>>(ei, deg, x, (uint4*)xb,
                                   W1l, W1r, (uint4*)Bp1, W2l, W2r, (uint4*)Bp2);
    scan_reduce<<<NB, 256, 0, stream>>>(deg, partial, N_NODES);
    scan_final2<<<NB, 256, 0, stream>>>(deg, partial, rowptr, N_NODES, E_EDGES, NB);
    fill_csr<<<2500, 256, 0, stream>>>(ei, rowptr, cursor, col, E_EDGES);

    sage_l1<<<N_NODES / 16, 256, 0, stream>>>(
        (const uint4*)xb, (const unsigned short*)xb, rowptr, col,
        (const unsigned short*)Bp1, (const unsigned short*)Bp2,
        b1, b2, (unsigned short*)Zb, out);

    gather_add<<<(N_NODES * 8 + 255) / 256, 256, 0, stream>>>(
        (const uint4*)Zb, rowptr, col, out, N_NODES);
}

// Round 10
// 209.369 us; speedup vs baseline: 1.5758x; 1.0385x over previous
//
#include <hip/hip_runtime.h>
#include <cstddef>

static constexpr int N_NODES = 50000;
static constexpr int E_EDGES = 640000;
static constexpr int F = 128;

typedef __bf16 b8 __attribute__((ext_vector_type(8)));
typedef float  f4 __attribute__((ext_vector_type(4)));
typedef float  f2 __attribute__((ext_vector_type(2)));

__device__ inline unsigned short f2bf(float f) {           // RTN-even
    unsigned u = __float_as_uint(f);
    u += 0x7FFF + ((u >> 16) & 1);
    return (unsigned short)(u >> 16);
}
__device__ inline float bflo(unsigned u) { return __uint_as_float(u << 16); }
__device__ inline float bfhi(unsigned u) { return __uint_as_float(u & 0xFFFF0000u); }

__device__ inline void acc8(float* s, uint4 u) {
    s[0] += bflo(u.x); s[1] += bfhi(u.x);
    s[2] += bflo(u.y); s[3] += bfhi(u.y);
    s[4] += bflo(u.z); s[5] += bfhi(u.z);
    s[6] += bflo(u.w); s[7] += bfhi(u.w);
}

// decode 8 fp8(e4m3) from uint2 and accumulate
__device__ inline void accq(float* s, uint2 u) {
    f2 p;
    p = __builtin_amdgcn_cvt_pk_f32_fp8(u.x, false); s[0] += p.x; s[1] += p.y;
    p = __builtin_amdgcn_cvt_pk_f32_fp8(u.x, true);  s[2] += p.x; s[3] += p.y;
    p = __builtin_amdgcn_cvt_pk_f32_fp8(u.y, false); s[4] += p.x; s[5] += p.y;
    p = __builtin_amdgcn_cvt_pk_f32_fp8(u.y, true);  s[6] += p.x; s[7] += p.y;
}

// ---------------- prep mega-kernel: count_deg | x->bf16+fp8 | pack W1 | pack W2 ----------------
template<int BN>
__device__ inline void pack_w_body(int t, const float* __restrict__ Wl,
                                   const float* __restrict__ Wr, uint4* __restrict__ Bp) {
    constexpr int NTg = BN / 16;
    int wid = t >> 6, lane = t & 63;
    if (wid >= 8 * NTg) return;
    int kq = lane >> 4, m = lane & 15;
    int kt = wid / NTg, nt = wid % NTg;
    unsigned short tmp[8];
#pragma unroll
    for (int j = 0; j < 8; ++j) {
        int k = kt * 32 + kq * 8 + j;
        const float* W = (k < 128) ? Wl : Wr;
        tmp[j] = f2bf(W[(size_t)(k & 127) * BN + nt * 16 + m]);
    }
    uint4 u;
    u.x = tmp[0] | ((unsigned)tmp[1] << 16);
    u.y = tmp[2] | ((unsigned)tmp[3] << 16);
    u.z = tmp[4] | ((unsigned)tmp[5] << 16);
    u.w = tmp[6] | ((unsigned)tmp[7] << 16);
    Bp[wid * 64 + lane] = u;
}

__global__ __launch_bounds__(256)
void prep(const int* __restrict__ ei, int* __restrict__ deg,
          const float* __restrict__ x, uint4* __restrict__ xb, uint2* __restrict__ xq,
          const float* __restrict__ W1l, const float* __restrict__ W1r, uint4* __restrict__ Bp1,
          const float* __restrict__ W2l, const float* __restrict__ W2r, uint4* __restrict__ Bp2) {
    int b = blockIdx.x, tid = threadIdx.x;
    if (b < 2500) {                       // count_deg (E = 2500*256 exact)
        int e = b * 256 + tid;
        atomicAdd(&deg[ei[E_EDGES + e]], 1);
    } else if (b < 5625) {                // x -> bf16 + fp8 (n8 = 3125*256 exact)
        int i = (b - 2500) * 256 + tid;
        const float4* s = (const float4*)x + (size_t)i * 2;
        float4 v0 = s[0], v1 = s[1];
        uint4 u;
        u.x = f2bf(v0.x) | ((unsigned)f2bf(v0.y) << 16);
        u.y = f2bf(v0.z) | ((unsigned)f2bf(v0.w) << 16);
        u.z = f2bf(v1.x) | ((unsigned)f2bf(v1.y) << 16);
        u.w = f2bf(v1.z) | ((unsigned)f2bf(v1.w) << 16);
        xb[i] = u;
        uint2 q;
        q.x = __builtin_amdgcn_cvt_pk_fp8_f32(v0.x, v0.y, 0, false);
        q.x = __builtin_amdgcn_cvt_pk_fp8_f32(v0.z, v0.w, q.x, true);
        q.y = __builtin_amdgcn_cvt_pk_fp8_f32(v1.x, v1.y, 0, false);
        q.y = __builtin_amdgcn_cvt_pk_fp8_f32(v1.z, v1.w, q.y, true);
        xq[i] = q;
    } else if (b < 5641) {                // pack W1 (64 waves)
        pack_w_body<128>((b - 5625) * 256 + tid, W1l, W1r, Bp1);
    } else {                              // pack W2 (32 waves)
        pack_w_body<64>((b - 5641) * 256 + tid, W2l, W2r, Bp2);
    }
}

// ---------------- scan (2 kernels): reduce, then fused partials+final ----------------
__global__ void scan_reduce(const int* __restrict__ deg, int* __restrict__ partial, int N) {
    __shared__ int s[256];
    int tid = threadIdx.x;
    int i = blockIdx.x * 256 + tid;
    s[tid] = (i < N) ? deg[i] : 0;
    __syncthreads();
    for (int off = 128; off > 0; off >>= 1) {
        if (tid < off) s[tid] += s[tid + off];
        __syncthreads();
    }
    if (tid == 0) partial[blockIdx.x] = s[0];
}

__global__ void scan_final2(const int* __restrict__ deg, const int* __restrict__ partial,
                            int* __restrict__ rowptr, int N, int E, int NB) {
    __shared__ int p[256];
    __shared__ int poffb;
    int tid = threadIdx.x;
    int pv = (tid < NB) ? partial[tid] : 0;
    p[tid] = pv;
    __syncthreads();
    for (int off = 1; off < 256; off <<= 1) {
        int t = (tid >= off) ? p[tid - off] : 0;
        __syncthreads();
        p[tid] += t;
        __syncthreads();
    }
    if (tid == 0) poffb = p[blockIdx.x] - partial[blockIdx.x];   // exclusive
    __syncthreads();
    int i = blockIdx.x * 256 + tid;
    int v = (i < N) ? deg[i] : 0;
    p[tid] = v;
    __syncthreads();
    for (int off = 1; off < 256; off <<= 1) {
        int t = (tid >= off) ? p[tid - off] : 0;
        __syncthreads();
        p[tid] += t;
        __syncthreads();
    }
    if (i < N) rowptr[i] = poffb + p[tid] - v;
    if (i == N - 1) rowptr[N] = E;
}

__global__ void fill_csr(const int* __restrict__ ei, const int* __restrict__ rowptr,
                         int* __restrict__ cursor, int* __restrict__ col, int E) {
    int e = blockIdx.x * blockDim.x + threadIdx.x;
    if (e >= E) return;
    int s = ei[e], d = ei[E + e];
    int off = atomicAdd(&cursor[d], 1);
    col[rowptr[d] + off] = s;
}

// ---------------- Fused L1 + L2-projections ----------------
// Phase 1: gather-mean of x (fp8 table, uint2 loads: 16 lanes x 8 B = 128 B row).
// Phase 2: h = relu([agg|self]@[W1l;W1r] + b1) -> Hlds (self path bf16).
// Phase 3: Z = h@W2l (bf16 -> Zb), S = h@W2r + b2 (f32 -> out).
__global__ __launch_bounds__(256)
void sage_l1(const uint2* __restrict__ featq,
             const unsigned short* __restrict__ featb,
             const int* __restrict__ rowptr,
             const int* __restrict__ col,
             const unsigned short* __restrict__ Bp1,
             const unsigned short* __restrict__ Bp2,
             const float* __restrict__ b1,
             const float* __restrict__ b2,
             unsigned short* __restrict__ Zb,
             float* __restrict__ out) {
    constexpr int LDW = 68;                    // Alds row stride (dwords) = 272 B
    __shared__ unsigned Alds[16 * LDW];
    __shared__ unsigned short Hlds[16 * 136];  // h tile, stride 136 shorts = 272 B

    const int tid  = threadIdx.x;
    const int wv   = tid >> 6;
    const int lane = tid & 63;
    const int c    = lane & 15;                // 8-byte chunk within fp8 row
    const int g    = lane >> 4;                // node-slot within wave (0..3)
    const int node0 = blockIdx.x * 16;
    const int node  = node0 + wv * 4 + g;

    // ---- Phase 1: gather + mean over fp8 rows (one node per 16-lane group) ----
    {
        int jb = rowptr[node], je = rowptr[node + 1];
        float s0[8] = {0.f,0.f,0.f,0.f,0.f,0.f,0.f,0.f};
        float s1[8] = {0.f,0.f,0.f,0.f,0.f,0.f,0.f,0.f};
        float s2[8] = {0.f,0.f,0.f,0.f,0.f,0.f,0.f,0.f};
        float s3[8] = {0.f,0.f,0.f,0.f,0.f,0.f,0.f,0.f};
        int j = jb;
        for (; j + 3 < je; j += 4) {
            uint2 u0 = featq[(size_t)col[j + 0] * 16 + c];
            uint2 u1 = featq[(size_t)col[j + 1] * 16 + c];
            uint2 u2 = featq[(size_t)col[j + 2] * 16 + c];
            uint2 u3 = featq[(size_t)col[j + 3] * 16 + c];
            accq(s0, u0); accq(s1, u1); accq(s2, u2); accq(s3, u3);
        }
        for (; j < je; ++j) {
            uint2 u0 = featq[(size_t)col[j] * 16 + c];
            accq(s0, u0);
        }
        int d = je - jb;
        float inv = 1.0f / (float)(d > 0 ? d : 1);
        float r[8];
#pragma unroll
        for (int k = 0; k < 8; ++k) r[k] = ((s0[k] + s1[k]) + (s2[k] + s3[k])) * inv;
        uint4 o;
        o.x = f2bf(r[0]) | ((unsigned)f2bf(r[1]) << 16);
        o.y = f2bf(r[2]) | ((unsigned)f2bf(r[3]) << 16);
        o.z = f2bf(r[4]) | ((unsigned)f2bf(r[5]) << 16);
        o.w = f2bf(r[6]) | ((unsigned)f2bf(r[7]) << 16);
        *((uint4*)&Alds[(wv * 4 + g) * LDW + c * 4]) = o;
    }
    __syncthreads();

    // ---- Phase 2: L1 MFMA, h -> Hlds ----
    const int m  = lane & 15;
    const int kq = lane >> 4;
    const unsigned short* srow = featb + (size_t)(node0 + m) * F + kq * 8;

    f4 zero = {0.f, 0.f, 0.f, 0.f};
    f4 acc[2] = {zero, zero};
#pragma unroll
    for (int kt = 0; kt < 8; ++kt) {
        b8 a;
        if (kt < 4) a = *((const b8*)((const char*)Alds + m * 272 + kt * 64 + kq * 16));
        else        a = *((const b8*)(srow + (kt - 4) * 32));
#pragma unroll
        for (int t = 0; t < 2; ++t) {
            int nt = wv * 2 + t;
            b8 b = *((const b8*)(Bp1 + ((size_t)(kt * 8 + nt) * 64 + lane) * 8));
            acc[t] = __builtin_amdgcn_mfma_f32_16x16x32_bf16(a, b, acc[t], 0, 0, 0);
        }
    }
    {
        int rowb = kq * 4;
#pragma unroll
        for (int t = 0; t < 2; ++t) {
            int cc = (wv * 2 + t) * 16 + m;
            float bv = b1[cc];
#pragma unroll
            for (int r = 0; r < 4; ++r) {
                float v = fmaxf(acc[t][r] + bv, 0.0f);
                Hlds[(rowb + r) * 136 + cc] = f2bf(v);
            }
        }
    }
    __syncthreads();

    // ---- Phase 3: Z = h@W2l (bf16), S = h@W2r + b2 (f32 -> out) ----
    f4 accZ = zero, accS = zero;
#pragma unroll
    for (int kt = 0; kt < 4; ++kt) {
        b8 a = *((const b8*)((const char*)Hlds + m * 272 + kt * 64 + kq * 16));
        b8 bz = *((const b8*)(Bp2 + ((size_t)(kt * 4 + wv) * 64 + lane) * 8));
        b8 bs = *((const b8*)(Bp2 + ((size_t)((kt + 4) * 4 + wv) * 64 + lane) * 8));
        accZ = __builtin_amdgcn_mfma_f32_16x16x32_bf16(a, bz, accZ, 0, 0, 0);
        accS = __builtin_amdgcn_mfma_f32_16x16x32_bf16(a, bs, accS, 0, 0, 0);
    }
    {
        int rowg = node0 + kq * 4;
        int cc = wv * 16 + m;
        float bv = b2[cc];
#pragma unroll
        for (int r = 0; r < 4; ++r) {
            Zb[(size_t)(rowg + r) * 64 + cc] = f2bf(accZ[r]);
            out[(size_t)(rowg + r) * 64 + cc] = accS[r] + bv;
        }
    }
}

// ---------------- Layer-2 gather: out += mean_agg(Z) (Z bf16, 128 B rows) ----------------
__global__ __launch_bounds__(256)
void gather_add(const uint4* __restrict__ Zv,
                const int* __restrict__ rowptr,
                const int* __restrict__ col,
                float* __restrict__ out, int N) {
    int t = blockIdx.x * 256 + threadIdx.x;
    int node = t >> 3;
    if (node >= N) return;
    int c = t & 7;                        // uint4 chunk within Z row

    int jb = rowptr[node], je = rowptr[node + 1];
    float s0[8] = {0.f,0.f,0.f,0.f,0.f,0.f,0.f,0.f};
    float s1[8] = {0.f,0.f,0.f,0.f,0.f,0.f,0.f,0.f};
    float s2[8] = {0.f,0.f,0.f,0.f,0.f,0.f,0.f,0.f};
    float s3[8] = {0.f,0.f,0.f,0.f,0.f,0.f,0.f,0.f};
    int j = jb;
    for (; j + 3 < je; j += 4) {
        uint4 u0 = Zv[(size_t)col[j + 0] * 8 + c];
        uint4 u1 = Zv[(size_t)col[j + 1] * 8 + c];
        uint4 u2 = Zv[(size_t)col[j + 2] * 8 + c];
        uint4 u3 = Zv[(size_t)col[j + 3] * 8 + c];
        acc8(s0, u0); acc8(s1, u1); acc8(s2, u2); acc8(s3, u3);
    }
    for (; j < je; ++j) {
        uint4 u0 = Zv[(size_t)col[j] * 8 + c];
        acc8(s0, u0);
    }
    int d = je - jb;
    float inv = 1.0f / (float)(d > 0 ? d : 1);
    float* op = out + (size_t)node * 64 + c * 8;
    float4 o0 = *((float4*)op);
    float4 o1 = *((float4*)(op + 4));
    o0.x += ((s0[0] + s1[0]) + (s2[0] + s3[0])) * inv;
    o0.y += ((s0[1] + s1[1]) + (s2[1] + s3[1])) * inv;
    o0.z += ((s0[2] + s1[2]) + (s2[2] + s3[2])) * inv;
    o0.w += ((s0[3] + s1[3]) + (s2[3] + s3[3])) * inv;
    o1.x += ((s0[4] + s1[4]) + (s2[4] + s3[4])) * inv;
    o1.y += ((s0[5] + s1[5]) + (s2[5] + s3[5])) * inv;
    o1.z += ((s0[6] + s1[6]) + (s2[6] + s3[6])) * inv;
    o1.w += ((s0[7] + s1[7]) + (s2[7] + s3[7])) * inv;
    *((float4*)op) = o0;
    *((float4*)(op + 4)) = o1;
}

// ---------------- Launch ----------------

extern "C" void kernel_launch(void* const* d_in, const int* in_sizes, int n_in,
                              void* d_out, int out_size, void* d_ws, size_t ws_size,
                              hipStream_t stream) {
    const float* x   = (const float*)d_in[0];
    const int*   ei  = (const int*)d_in[1];
    const float* W1l = (const float*)d_in[2];
    const float* b1  = (const float*)d_in[3];
    const float* W1r = (const float*)d_in[4];
    const float* W2l = (const float*)d_in[5];
    const float* b2  = (const float*)d_in[6];
    const float* W2r = (const float*)d_in[7];
    float* out = (float*)d_out;

    // ws layout (uint units): Zb[N*32] xb[N*64] xq[N*32] Bp1[16384] Bp2[8192]
    //                         col[E] rowptr[N+1] deg[N] cursor[N] partial[256]
    unsigned* Zb    = (unsigned*)d_ws;
    unsigned* xb    = Zb + (size_t)N_NODES * 32;
    unsigned* xq    = xb + (size_t)N_NODES * 64;
    unsigned* Bp1   = xq + (size_t)N_NODES * 32;
    unsigned* Bp2   = Bp1 + 16384;
    int* col        = (int*)(Bp2 + 8192);
    int* rowptr     = col + E_EDGES;
    int* deg        = rowptr + (N_NODES + 1);
    int* cursor     = deg + N_NODES;
    int* partial    = cursor + N_NODES;

    const int NB = (N_NODES + 255) / 256;   // 196
    hipMemsetAsync(deg, 0, (size_t)2 * N_NODES * sizeof(int), stream);  // deg+cursor

    prep<<<5649, 256, 0, stream>>>(ei, deg, x, (uint4*)xb, (uint2*)xq,
                                   W1l, W1r, (uint4*)Bp1, W2l, W2r, (uint4*)Bp2);
    scan_reduce<<<NB, 256, 0, stream>>>(deg, partial, N_NODES);
    scan_final2<<<NB, 256, 0, stream>>>(deg, partial, rowptr, N_NODES, E_EDGES, NB);
    fill_csr<<<2500, 256, 0, stream>>>(ei, rowptr, cursor, col, E_EDGES);

    sage_l1<<<N_NODES / 16, 256, 0, stream>>>(
        (const uint2*)xq, (const unsigned short*)xb, rowptr, col,
        (const unsigned short*)Bp1, (const unsigned short*)Bp2,
        b1, b2, (unsigned short*)Zb, out);

    gather_add<<<(N_NODES * 8 + 255) / 256, 256, 0, stream>>>(
        (const uint4*)Zb, rowptr, col, out, N_NODES);
}